// Round 7
// baseline (526.477 us; speedup 1.0000x reference)
//
#include <hip/hip_runtime.h>

// LSTM: B=8192, T=512, IN=8, H=64, OUT=1
// R11: software-pipelined two-tile block (1 block/CU, grid 256, 4 waves).
//   Counters at R9/R10 show step = VALU(58%) + MFMA(27%) + idle(15%):
//   MFMA never hides under VALU because post-barrier each wave's act depends
//   on its own just-issued MFMA chain (in-order issue => no independent
//   VALU during the MFMA window), and cross-block anti-phase never holds
//   (R10 stagger null). Fix by construction: two independent 16-batch tiles
//   per block, half-step phase-shifted:
//     interval A: MFMA(tile1, t)   || act(tile0, t)  -> write h0 -> bar
//     interval B: MFMA(tile0, t+1) || act(tile1, t)  -> write h1 -> bar
//   Every interval starts with dependency-free act VALU to fill the MFMA
//   pipe shadow. (R7 failed because both tiles' acts depended on
//   same-interval MFMAs.) setprio/stagger dropped (1 wave/SIMD).
// R9: x frags from LDS off critical path; barrier diet. 334.0 us.
// R8: transposed MFMA orientation (A=weights, B=h/x); packed b64 h-writeback;
//   x-term as 16x16x16 MFMA. 339.6 us.
// R5: transcendental diet (5 exp2 + 2 rcp / element, scaled-domain chat).
// R4: x staged through double-buffered LDS in 16-step chunks.
// R2: activation scale folded into weights (-log2e i/f/o, +2log2e g).
// MFMA layouts (m89/m91/m120 verified):
//   A[m=lane&15][k=(lane>>4)*8+j] (x32) / [k=(lane>>4)*4+j] (x16),
//   B[k][n=lane&15], C/D: col=lane&15, row=(lane>>4)*4+reg.

typedef _Float16 f16_t;
typedef _Float16 half8 __attribute__((ext_vector_type(8)));
typedef _Float16 half4 __attribute__((ext_vector_type(4)));
typedef __fp16 fp16x2 __attribute__((ext_vector_type(2)));
typedef float floatx2 __attribute__((ext_vector_type(2)));
typedef float floatx4 __attribute__((ext_vector_type(4)));

#define Bn 8192
#define Tn 512
#define INn 8
#define Hn 64
#define BT 16          // rows per tile
#define NT 2           // tiles per block -> 32 batch rows/block
#define CHUNK 16
#define NCHUNK (Tn / CHUNK)
#define HSTRIDE 72   // f16; row = 144B: b128 reads 16B-aligned, 2-way banks (free)
#define XROW 24      // f16 per batch row: 8 real + 8 zero + 8 pad; 48B, 16B-aligned

// lgkmcnt-only barrier: publishes LDS writes, leaves vmem loads in flight.
#define SOFT_BARRIER() asm volatile("s_waitcnt lgkmcnt(0)\n\ts_barrier" ::: "memory")

__device__ __forceinline__ floatx2 act_pair(float zi0, float zi1,
                                            float zf0, float zf1,
                                            float zg0, float zg1,
                                            float zo0, float zo1,
                                            floatx2& chat) {
  const floatx2 one  = {1.f, 1.f};
  const float  K2   = 2.8853900817779268f;  // 2*log2(e)
  const floatx2 K2v  = {K2, K2};
  const floatx2 mK2v = {-K2, -K2};
  const floatx2 clmp = {126.f, 126.f};
  floatx2 A = {__builtin_amdgcn_exp2f(zi0), __builtin_amdgcn_exp2f(zi1)};
  floatx2 G = {__builtin_amdgcn_exp2f(zg0), __builtin_amdgcn_exp2f(zg1)};
  floatx2 F = {__builtin_amdgcn_exp2f(zf0), __builtin_amdgcn_exp2f(zf1)};
  floatx2 O = {__builtin_amdgcn_exp2f(zo0), __builtin_amdgcn_exp2f(zo1)};
  floatx2 PA  = A + one;
  floatx2 PG  = G + one;
  floatx2 PF  = F + one;
  floatx2 PAG = PA * PG;
  floatx2 num = __builtin_elementwise_fma(G, K2v, mK2v) * PF;  // K(G-1)(1+F)
  floatx2 s   = __builtin_elementwise_fma(chat, PAG, num);
  floatx2 P3  = PF * PAG;
  floatx2 R   = {__builtin_amdgcn_rcpf(P3.x), __builtin_amdgcn_rcpf(P3.y)};
  chat = __builtin_elementwise_min(s * R, clmp);
  floatx2 C2 = {__builtin_amdgcn_exp2f(chat.x), __builtin_amdgcn_exp2f(chat.y)};
  floatx2 P4 = (O + one) * (C2 + one);
  floatx2 Rh = {__builtin_amdgcn_rcpf(P4.x), __builtin_amdgcn_rcpf(P4.y)};
  return (C2 - one) * Rh;  // h = o * tanh(c)
}

__global__ __launch_bounds__(256, 1)
void lstm_fused(const float* __restrict__ xg,
                const float* __restrict__ W_ih,
                const float* __restrict__ W_hh,
                const float* __restrict__ b_ih,
                const float* __restrict__ b_hh,
                const float* __restrict__ W_fc,
                const float* __restrict__ b_fc,
                float* __restrict__ out)
{
  __shared__ alignas(16) f16_t hbuf[NT][2][BT][HSTRIDE];       // [tile][par][batch][unit]
  __shared__ alignas(16) f16_t xlds[NT][2][CHUNK][BT][XROW];   // [tile][chpar][tt][batch][feat]

  const int tid   = threadIdx.x;
  const int wv    = tid >> 6;     // wave 0..3 -> hidden units 16w..16w+15
  const int lane  = tid & 63;
  const int n     = lane & 15;    // A-row (unit) / B-col (batch) / D-col
  const int q     = lane >> 4;    // quad
  const int bbase = blockIdx.x * (BT * NT);

  const float LOG2E = 1.4426950408889634f;

  // ---- weight A-fragments, pre-scaled, resident in VGPRs (shared by tiles).
  half8 bf[4][2];
  half4 bfx[4];
  #pragma unroll
  for (int g = 0; g < 4; ++g) {
    const float sc = (g == 2) ? (2.f * LOG2E) : (-LOG2E);
    const int C = g * 64 + wv * 16 + n;   // global gate-unit row
    #pragma unroll
    for (int c = 0; c < 2; ++c) {
      half8 v;
      #pragma unroll
      for (int j = 0; j < 8; ++j) {
        const int k = c * 32 + q * 8 + j;          // < 64 always
        v[j] = (f16_t)(W_hh[C * Hn + k] * sc);
      }
      bf[g][c] = v;
    }
    half4 vx;
    #pragma unroll
    for (int j = 0; j < 4; ++j) {
      const int k = q * 4 + j;                     // [0,16)
      vx[j] = (f16_t)((k < INn) ? (W_ih[C * INn + k] * sc) : 0.f);
    }
    bfx[g] = vx;
  }

  // ---- scaled biases -> persistent MFMA C-operand registers.
  const int u0 = wv * 16 + q * 4;   // lane covers units u0..u0+3
  floatx4 bi, bfv, bg, bo;
  #pragma unroll
  for (int r = 0; r < 4; ++r) {
    const int uu = u0 + r;
    bi[r]  = -(b_ih[uu]        + b_hh[uu])        * LOG2E;
    bfv[r] = -(b_ih[64 + uu]   + b_hh[64 + uu])   * LOG2E;
    bg[r]  =  (b_ih[128 + uu]  + b_hh[128 + uu])  * (2.f * LOG2E);
    bo[r]  = -(b_ih[192 + uu]  + b_hh[192 + uu])  * LOG2E;
  }

  // ---- x staging assignment: lane -> (row, tt); 16-lane groups coalesce 512B
  const int row_s = tid >> 4;   // 0..15 batch row within tile
  const int tt_s  = tid & 15;   // 0..15 timestep within chunk
  const float* xps0 = xg + ((size_t)(bbase + row_s) * Tn + tt_s) * INn;
  const float* xps1 = xps0 + (size_t)BT * Tn * INn;

  // ---- one-time LDS init: hbuf = 0 (both tiles/parities); x k-tails = 0;
  //      stage chunk 0 (both tiles)
  for (int i = tid; i < NT * 2 * BT * HSTRIDE; i += 256)
    ((f16_t*)hbuf)[i] = (f16_t)0.f;
  {
    const half8 z = {};
    for (int r = tid; r < NT * 2 * CHUNK * BT; r += 256) {
      f16_t* base = ((f16_t*)xlds) + (size_t)r * XROW;
      *(half8*)(base + 8)  = z;
      *(half8*)(base + 16) = z;
    }
  }
  {
    float4 a  = *(const float4*)(xps0);
    float4 b2 = *(const float4*)(xps0 + 4);
    union { half8 v; fp16x2 h2[4]; } P;
    P.h2[0] = __builtin_amdgcn_cvt_pkrtz(a.x, a.y);
    P.h2[1] = __builtin_amdgcn_cvt_pkrtz(a.z, a.w);
    P.h2[2] = __builtin_amdgcn_cvt_pkrtz(b2.x, b2.y);
    P.h2[3] = __builtin_amdgcn_cvt_pkrtz(b2.z, b2.w);
    *(half8*)&xlds[0][0][tt_s][row_s][0] = P.v;
    a  = *(const float4*)(xps1);
    b2 = *(const float4*)(xps1 + 4);
    P.h2[0] = __builtin_amdgcn_cvt_pkrtz(a.x, a.y);
    P.h2[1] = __builtin_amdgcn_cvt_pkrtz(a.z, a.w);
    P.h2[2] = __builtin_amdgcn_cvt_pkrtz(b2.x, b2.y);
    P.h2[3] = __builtin_amdgcn_cvt_pkrtz(b2.z, b2.w);
    *(half8*)&xlds[1][0][tt_s][row_s][0] = P.v;
  }
  // preload chunk 1 into registers (written to LDS at ch=0, tt=0)
  float4 pa0 = *(const float4*)(xps0 + CHUNK * INn);
  float4 pb0 = *(const float4*)(xps0 + CHUNK * INn + 4);
  float4 pa1 = *(const float4*)(xps1 + CHUNK * INn);
  float4 pb1 = *(const float4*)(xps1 + CHUNK * INn + 4);

  __syncthreads();  // init + chunk 0 visible (full drain, once)

  floatx2 chat0_01 = {0.f, 0.f}, chat0_23 = {0.f, 0.f};  // tile0 cell state
  floatx2 chat1_01 = {0.f, 0.f}, chat1_23 = {0.f, 0.f};  // tile1 cell state

  // ---- prologue: MFMA(tile0, t=0) using h0 = 0 and x(t=0)
  floatx4 t0i, t0f, t0g, t0o;
  {
    const half8 d0 = *(const half8*)&hbuf[0][0][n][q * 8];
    const half8 d1 = *(const half8*)&hbuf[0][0][n][32 + q * 8];
    const half4 bx0 = *(const half4*)&xlds[0][0][0][n][q * 4];
    t0i = __builtin_amdgcn_mfma_f32_16x16x32_f16(bf[0][0], d0, bi,  0, 0, 0);
    t0f = __builtin_amdgcn_mfma_f32_16x16x32_f16(bf[1][0], d0, bfv, 0, 0, 0);
    t0g = __builtin_amdgcn_mfma_f32_16x16x32_f16(bf[2][0], d0, bg,  0, 0, 0);
    t0o = __builtin_amdgcn_mfma_f32_16x16x32_f16(bf[3][0], d0, bo,  0, 0, 0);
    t0i = __builtin_amdgcn_mfma_f32_16x16x32_f16(bf[0][1], d1, t0i, 0, 0, 0);
    t0f = __builtin_amdgcn_mfma_f32_16x16x32_f16(bf[1][1], d1, t0f, 0, 0, 0);
    t0g = __builtin_amdgcn_mfma_f32_16x16x32_f16(bf[2][1], d1, t0g, 0, 0, 0);
    t0o = __builtin_amdgcn_mfma_f32_16x16x32_f16(bf[3][1], d1, t0o, 0, 0, 0);
    t0i = __builtin_amdgcn_mfma_f32_16x16x16f16(bfx[0], bx0, t0i, 0, 0, 0);
    t0f = __builtin_amdgcn_mfma_f32_16x16x16f16(bfx[1], bx0, t0f, 0, 0, 0);
    t0g = __builtin_amdgcn_mfma_f32_16x16x16f16(bfx[2], bx0, t0g, 0, 0, 0);
    t0o = __builtin_amdgcn_mfma_f32_16x16x16f16(bfx[3], bx0, t0o, 0, 0, 0);
  }

  for (int ch = 0; ch < NCHUNK; ++ch) {
    #pragma unroll
    for (int tt = 0; tt < CHUNK; ++tt) {
      const int p  = tt & 1;        // parity holding h(t-1)
      const int pn = p ^ 1;         // parity receiving h(t)
      const int cp = ch & 1;

      // ================= interval A: MFMA(tile1,t) || act(tile0,t) ========
      const half8 c0  = *(const half8*)&hbuf[1][p][n][q * 8];
      const half8 c1  = *(const half8*)&hbuf[1][p][n][32 + q * 8];
      const half4 bx1 = *(const half4*)&xlds[1][cp][tt][n][q * 4];

      if (tt == 0) {
        // publish chunk ch+1 (both tiles) into the opposite chunk parity;
        // published by this interval's barrier, consumed next chunk.
        union { half8 v; fp16x2 h2[4]; } P;
        P.h2[0] = __builtin_amdgcn_cvt_pkrtz(pa0.x, pa0.y);
        P.h2[1] = __builtin_amdgcn_cvt_pkrtz(pa0.z, pa0.w);
        P.h2[2] = __builtin_amdgcn_cvt_pkrtz(pb0.x, pb0.y);
        P.h2[3] = __builtin_amdgcn_cvt_pkrtz(pb0.z, pb0.w);
        *(half8*)&xlds[0][(ch + 1) & 1][tt_s][row_s][0] = P.v;
        P.h2[0] = __builtin_amdgcn_cvt_pkrtz(pa1.x, pa1.y);
        P.h2[1] = __builtin_amdgcn_cvt_pkrtz(pa1.z, pa1.w);
        P.h2[2] = __builtin_amdgcn_cvt_pkrtz(pb1.x, pb1.y);
        P.h2[3] = __builtin_amdgcn_cvt_pkrtz(pb1.z, pb1.w);
        *(half8*)&xlds[1][(ch + 1) & 1][tt_s][row_s][0] = P.v;
      }
      if (tt == 1) {
        // reissue global prefetch (chunk ch+2, wrapped); in flight across
        // the soft barriers, consumed 15 steps later.
        const int chn = (ch + 2 < NCHUNK) ? (ch + 2) : (ch + 2 - NCHUNK);
        pa0 = *(const float4*)(xps0 + (size_t)chn * CHUNK * INn);
        pb0 = *(const float4*)(xps0 + (size_t)chn * CHUNK * INn + 4);
        pa1 = *(const float4*)(xps1 + (size_t)chn * CHUNK * INn);
        pb1 = *(const float4*)(xps1 + (size_t)chn * CHUNK * INn + 4);
      }

      floatx4 u1i = __builtin_amdgcn_mfma_f32_16x16x32_f16(bf[0][0], c0, bi,  0, 0, 0);
      floatx4 u1f = __builtin_amdgcn_mfma_f32_16x16x32_f16(bf[1][0], c0, bfv, 0, 0, 0);
      floatx4 u1g = __builtin_amdgcn_mfma_f32_16x16x32_f16(bf[2][0], c0, bg,  0, 0, 0);
      floatx4 u1o = __builtin_amdgcn_mfma_f32_16x16x32_f16(bf[3][0], c0, bo,  0, 0, 0);
      u1i = __builtin_amdgcn_mfma_f32_16x16x32_f16(bf[0][1], c1, u1i, 0, 0, 0);
      u1f = __builtin_amdgcn_mfma_f32_16x16x32_f16(bf[1][1], c1, u1f, 0, 0, 0);
      u1g = __builtin_amdgcn_mfma_f32_16x16x32_f16(bf[2][1], c1, u1g, 0, 0, 0);
      u1o = __builtin_amdgcn_mfma_f32_16x16x32_f16(bf[3][1], c1, u1o, 0, 0, 0);
      u1i = __builtin_amdgcn_mfma_f32_16x16x16f16(bfx[0], bx1, u1i, 0, 0, 0);
      u1f = __builtin_amdgcn_mfma_f32_16x16x16f16(bfx[1], bx1, u1f, 0, 0, 0);
      u1g = __builtin_amdgcn_mfma_f32_16x16x16f16(bfx[2], bx1, u1g, 0, 0, 0);
      u1o = __builtin_amdgcn_mfma_f32_16x16x16f16(bfx[3], bx1, u1o, 0, 0, 0);

      // act(tile0, t): gate sums in regs since interval B of step t-1 —
      // dependency-free VALU available from cycle 0 of this interval.
      {
        const floatx2 h01 = act_pair(t0i[0], t0i[1], t0f[0], t0f[1],
                                     t0g[0], t0g[1], t0o[0], t0o[1], chat0_01);
        const floatx2 h23 = act_pair(t0i[2], t0i[3], t0f[2], t0f[3],
                                     t0g[2], t0g[3], t0o[2], t0o[3], chat0_23);
        union { half4 v; fp16x2 h2[2]; } Wq;
        Wq.h2[0] = __builtin_amdgcn_cvt_pkrtz(h01.x, h01.y);
        Wq.h2[1] = __builtin_amdgcn_cvt_pkrtz(h23.x, h23.y);
        *(half4*)&hbuf[0][pn][n][u0] = Wq.v;
      }
      SOFT_BARRIER();

      // ============= interval B: MFMA(tile0,t+1) || act(tile1,t) ==========
      const int ntt = (tt + 1) & (CHUNK - 1);
      const int np  = (tt == CHUNK - 1) ? (cp ^ 1) : cp;
      const half8 d0  = *(const half8*)&hbuf[0][pn][n][q * 8];      // h0(t)
      const half8 d1  = *(const half8*)&hbuf[0][pn][n][32 + q * 8];
      const half4 bx0 = *(const half4*)&xlds[0][np][ntt][n][q * 4]; // x(t+1)

      t0i = __builtin_amdgcn_mfma_f32_16x16x32_f16(bf[0][0], d0, bi,  0, 0, 0);
      t0f = __builtin_amdgcn_mfma_f32_16x16x32_f16(bf[1][0], d0, bfv, 0, 0, 0);
      t0g = __builtin_amdgcn_mfma_f32_16x16x32_f16(bf[2][0], d0, bg,  0, 0, 0);
      t0o = __builtin_amdgcn_mfma_f32_16x16x32_f16(bf[3][0], d0, bo,  0, 0, 0);
      t0i = __builtin_amdgcn_mfma_f32_16x16x32_f16(bf[0][1], d1, t0i, 0, 0, 0);
      t0f = __builtin_amdgcn_mfma_f32_16x16x32_f16(bf[1][1], d1, t0f, 0, 0, 0);
      t0g = __builtin_amdgcn_mfma_f32_16x16x32_f16(bf[2][1], d1, t0g, 0, 0, 0);
      t0o = __builtin_amdgcn_mfma_f32_16x16x32_f16(bf[3][1], d1, t0o, 0, 0, 0);
      t0i = __builtin_amdgcn_mfma_f32_16x16x16f16(bfx[0], bx0, t0i, 0, 0, 0);
      t0f = __builtin_amdgcn_mfma_f32_16x16x16f16(bfx[1], bx0, t0f, 0, 0, 0);
      t0g = __builtin_amdgcn_mfma_f32_16x16x16f16(bfx[2], bx0, t0g, 0, 0, 0);
      t0o = __builtin_amdgcn_mfma_f32_16x16x16f16(bfx[3], bx0, t0o, 0, 0, 0);

      // act(tile1, t): u1* computed in interval A — dependency-free here.
      {
        const floatx2 h01 = act_pair(u1i[0], u1i[1], u1f[0], u1f[1],
                                     u1g[0], u1g[1], u1o[0], u1o[1], chat1_01);
        const floatx2 h23 = act_pair(u1i[2], u1i[3], u1f[2], u1f[3],
                                     u1g[2], u1g[3], u1o[2], u1o[3], chat1_23);
        union { half4 v; fp16x2 h2[2]; } Wq;
        Wq.h2[0] = __builtin_amdgcn_cvt_pkrtz(h01.x, h01.y);
        Wq.h2[1] = __builtin_amdgcn_cvt_pkrtz(h23.x, h23.y);
        *(half4*)&hbuf[1][pn][n][u0] = Wq.v;
      }
      SOFT_BARRIER();
      // (final iteration's t0* is garbage for t=512 — never consumed)
    }
  }

  // ---- epilogue: out[b] = h_T[b,:] . W_fc + b_fc   (h_T in parity 0)
  if (tid < 128) {
    const int tile = wv;          // wave 0 -> tile 0, wave 1 -> tile 1
    const int b = lane & 15;
    const int part = lane >> 4;
    float s = 0.f;
    #pragma unroll
    for (int k = 0; k < 16; ++k) {
      const int uu = part * 16 + k;
      s = __builtin_fmaf((float)hbuf[tile][0][b][uu], W_fc[uu], s);
    }
    s += __shfl_down(s, 32);
    s += __shfl_down(s, 16);
    if (lane < 16) out[bbase + tile * BT + b] = s + b_fc[0];
  }
}

extern "C" void kernel_launch(void* const* d_in, const int* in_sizes, int n_in,
                              void* d_out, int out_size, void* d_ws, size_t ws_size,
                              hipStream_t stream) {
  const float* x    = (const float*)d_in[0];
  const float* W_ih = (const float*)d_in[1];
  const float* W_hh = (const float*)d_in[2];
  const float* b_ih = (const float*)d_in[3];
  const float* b_hh = (const float*)d_in[4];
  const float* W_fc = (const float*)d_in[5];
  const float* b_fc = (const float*)d_in[6];
  float* out = (float*)d_out;
  dim3 grid(Bn / (BT * NT)), block(256);
  hipLaunchKernelGGL(lstm_fused, grid, block, 0, stream,
                     x, W_ih, W_hh, b_ih, b_hh, W_fc, b_fc, out);
}

// Round 8
// 437.424 us; speedup vs baseline: 1.2036x; 1.2036x over previous
//
#include <hip/hip_runtime.h>

// LSTM: B=8192, T=512, IN=8, H=64, OUT=1
// R12 (on R9): transcendental diet II — pairwise rcp merge.
//   Counter invariant across R5/R8/R9/R11: VALUBusy*dur ~= 195 us constant
//   => VALU pipe demand is fixed; it is ~57% transcendental (28 quarter-rate
//   trans instrs/wave-step = 896 cyc/SIMD-step ~= measured VALUBusy).
//   Merge the two independent rcps in each act_pair (P3.x,P3.y) and
//   (P4.x,P4.y): rcp(x*y) + 3 muls replaces 2 rcps. 8 rcp -> 4 rcp per
//   wave-step (trans 28 -> 24). Exact algebra; overflow class unchanged.
//   R10's soft-barrier/stagger dropped (measured neutral-negative).
// R11/R7 (reverted): 1 block/CU topologies = -28..31%. 2 phase-independent
//   blocks/CU is mandatory (3 experiments).
// R9: chunk-top barrier removed; x frags chunk-preloaded; setprio around
//   MFMA cluster. 334.0 us.
// R8: transposed MFMA orientation (A=weights, B=h/x); packed b64 h-writeback;
//   x-term as 16x16x16 MFMA. 339.6 us.
// R5: transcendental diet I (5 exp2 + 2 rcp / element, scaled-domain chat).
// R4: x staged through double-buffered LDS in 16-step chunks.
// R2: activation scale folded into weights (-log2e i/f/o, +2log2e g).
// MFMA layouts (m89/m91/m120 verified):
//   A[m=lane&15][k=(lane>>4)*8+j] (x32) / [k=(lane>>4)*4+j] (x16),
//   B[k][n=lane&15], C/D: col=lane&15, row=(lane>>4)*4+reg.

typedef _Float16 f16_t;
typedef _Float16 half8 __attribute__((ext_vector_type(8)));
typedef _Float16 half4 __attribute__((ext_vector_type(4)));
typedef __fp16 fp16x2 __attribute__((ext_vector_type(2)));
typedef float floatx2 __attribute__((ext_vector_type(2)));
typedef float floatx4 __attribute__((ext_vector_type(4)));

#define Bn 8192
#define Tn 512
#define INn 8
#define Hn 64
#define BT 16
#define CHUNK 16
#define NCHUNK (Tn / CHUNK)
#define HSTRIDE 72   // f16; row = 144B: b128 reads 16B-aligned, 2-way banks (free)
#define XROW 24      // f16 per batch row: 8 real + 8 zero + 8 pad; 48B, 16B-aligned

__device__ __forceinline__ floatx2 act_pair(float zi0, float zi1,
                                            float zf0, float zf1,
                                            float zg0, float zg1,
                                            float zo0, float zo1,
                                            floatx2& chat) {
  const floatx2 one  = {1.f, 1.f};
  const float  K2   = 2.8853900817779268f;  // 2*log2(e)
  const floatx2 K2v  = {K2, K2};
  const floatx2 mK2v = {-K2, -K2};
  const floatx2 clmp = {126.f, 126.f};
  floatx2 A = {__builtin_amdgcn_exp2f(zi0), __builtin_amdgcn_exp2f(zi1)};
  floatx2 G = {__builtin_amdgcn_exp2f(zg0), __builtin_amdgcn_exp2f(zg1)};
  floatx2 F = {__builtin_amdgcn_exp2f(zf0), __builtin_amdgcn_exp2f(zf1)};
  floatx2 O = {__builtin_amdgcn_exp2f(zo0), __builtin_amdgcn_exp2f(zo1)};
  floatx2 PA  = A + one;
  floatx2 PG  = G + one;
  floatx2 PF  = F + one;
  floatx2 PAG = PA * PG;
  floatx2 num = __builtin_elementwise_fma(G, K2v, mK2v) * PF;  // K(G-1)(1+F)
  floatx2 s   = __builtin_elementwise_fma(chat, PAG, num);
  floatx2 P3  = PF * PAG;
  // merged reciprocal: 1 rcp + 3 muls instead of 2 rcps
  {
    const float r3 = __builtin_amdgcn_rcpf(P3.x * P3.y);
    const floatx2 r3v = {r3, r3};
    const floatx2 P3s = {P3.y, P3.x};
    chat = __builtin_elementwise_min(s * (r3v * P3s), clmp);
  }
  floatx2 C2 = {__builtin_amdgcn_exp2f(chat.x), __builtin_amdgcn_exp2f(chat.y)};
  floatx2 P4 = (O + one) * (C2 + one);
  {
    const float r4 = __builtin_amdgcn_rcpf(P4.x * P4.y);
    const floatx2 r4v = {r4, r4};
    const floatx2 P4s = {P4.y, P4.x};
    return (C2 - one) * (r4v * P4s);  // h = o * tanh(c)
  }
}

__global__ __launch_bounds__(256, 2)
void lstm_fused(const float* __restrict__ xg,
                const float* __restrict__ W_ih,
                const float* __restrict__ W_hh,
                const float* __restrict__ b_ih,
                const float* __restrict__ b_hh,
                const float* __restrict__ W_fc,
                const float* __restrict__ b_fc,
                float* __restrict__ out)
{
  __shared__ alignas(16) f16_t hbuf[2][BT][HSTRIDE];          // [batch][unit]
  __shared__ alignas(16) f16_t xlds[2][CHUNK][BT][XROW];      // [tt][batch][feat]

  const int tid   = threadIdx.x;
  const int wv    = tid >> 6;     // wave 0..3 -> hidden units 16w..16w+15
  const int lane  = tid & 63;
  const int n     = lane & 15;    // A-row (unit) / B-col (batch) / D-col
  const int q     = lane >> 4;    // quad
  const int bbase = blockIdx.x * BT;

  const float LOG2E = 1.4426950408889634f;

  // ---- weight A-fragments, pre-scaled, resident in VGPRs.
  half8 bf[4][2];
  half4 bfx[4];
  #pragma unroll
  for (int g = 0; g < 4; ++g) {
    const float sc = (g == 2) ? (2.f * LOG2E) : (-LOG2E);
    const int C = g * 64 + wv * 16 + n;   // global gate-unit row
    #pragma unroll
    for (int c = 0; c < 2; ++c) {
      half8 v;
      #pragma unroll
      for (int j = 0; j < 8; ++j) {
        const int k = c * 32 + q * 8 + j;          // < 64 always
        v[j] = (f16_t)(W_hh[C * Hn + k] * sc);
      }
      bf[g][c] = v;
    }
    half4 vx;
    #pragma unroll
    for (int j = 0; j < 4; ++j) {
      const int k = q * 4 + j;                     // [0,16)
      vx[j] = (f16_t)((k < INn) ? (W_ih[C * INn + k] * sc) : 0.f);
    }
    bfx[g] = vx;
  }

  // ---- scaled biases -> persistent MFMA C-operand registers.
  const int u0 = wv * 16 + q * 4;   // lane covers units u0..u0+3
  floatx4 bi, bfv, bg, bo;
  #pragma unroll
  for (int r = 0; r < 4; ++r) {
    const int uu = u0 + r;
    bi[r]  = -(b_ih[uu]        + b_hh[uu])        * LOG2E;
    bfv[r] = -(b_ih[64 + uu]   + b_hh[64 + uu])   * LOG2E;
    bg[r]  =  (b_ih[128 + uu]  + b_hh[128 + uu])  * (2.f * LOG2E);
    bo[r]  = -(b_ih[192 + uu]  + b_hh[192 + uu])  * LOG2E;
  }

  // ---- x staging assignment: lane -> (row, tt); 16-lane groups coalesce 512B
  const int row_s = tid >> 4;   // 0..15 batch row
  const int tt_s  = tid & 15;   // 0..15 timestep within chunk
  const float* xps = xg + ((size_t)(bbase + row_s) * Tn + tt_s) * INn;

  // ---- one-time LDS init (all writes disjoint -> single barrier):
  //   hbuf[0] = 0; x k-tails [8..24) = 0 (both parities); chunk 0 -> xlds[0]
  for (int i = tid; i < BT * HSTRIDE; i += 256) ((f16_t*)hbuf[0])[i] = (f16_t)0.f;
  {
    const half8 z = {};
    #pragma unroll
    for (int r = tid; r < 2 * CHUNK * BT; r += 256) {
      f16_t* base = &xlds[r >> 8][(r >> 4) & 15][r & 15][0];
      *(half8*)(base + 8)  = z;
      *(half8*)(base + 16) = z;
    }
  }
  {
    float4 a  = *(const float4*)(xps);
    float4 b2 = *(const float4*)(xps + 4);
    union { half8 v; fp16x2 h2[4]; } P;
    P.h2[0] = __builtin_amdgcn_cvt_pkrtz(a.x, a.y);
    P.h2[1] = __builtin_amdgcn_cvt_pkrtz(a.z, a.w);
    P.h2[2] = __builtin_amdgcn_cvt_pkrtz(b2.x, b2.y);
    P.h2[3] = __builtin_amdgcn_cvt_pkrtz(b2.z, b2.w);
    *(half8*)&xlds[0][tt_s][row_s][0] = P.v;
  }
  // preload chunk 1 into registers (written to LDS at ch=0, tt=0)
  float4 pa  = *(const float4*)(xps + CHUNK * INn);
  float4 pb2 = *(const float4*)(xps + CHUNK * INn + 4);

  __syncthreads();  // hbuf zero + x tails + chunk 0 visible

  floatx2 chat01 = {0.f, 0.f};  // scaled cell state, units u0+{0,1}
  floatx2 chat23 = {0.f, 0.f};  // units u0+{2,3}

  for (int ch = 0; ch < NCHUNK; ++ch) {
    // ---- chunk-top (no barrier): preload this chunk's 16 x fragments.
    // xlds[ch&1] was published by prev chunk's tt=15 barrier (ch=0: init).
    half4 bx[CHUNK];
    #pragma unroll
    for (int t = 0; t < CHUNK; ++t)
      bx[t] = *(const half4*)&xlds[ch & 1][t][n][q * 4];

    #pragma unroll
    for (int tt = 0; tt < CHUNK; ++tt) {
      const int p  = tt & 1;
      const int pn = p ^ 1;

      // post-barrier critical chain: h fragments only
      const half8 b0 = *(const half8*)&hbuf[p][n][q * 8];
      const half8 b1 = *(const half8*)&hbuf[p][n][32 + q * 8];

      __builtin_amdgcn_s_setprio(1);
      // D = W * (h|x) + bias; bias regs as first-MFMA C operand
      floatx4 ai = __builtin_amdgcn_mfma_f32_16x16x32_f16(bf[0][0], b0, bi,  0, 0, 0);
      floatx4 af = __builtin_amdgcn_mfma_f32_16x16x32_f16(bf[1][0], b0, bfv, 0, 0, 0);
      floatx4 ag = __builtin_amdgcn_mfma_f32_16x16x32_f16(bf[2][0], b0, bg,  0, 0, 0);
      floatx4 ao = __builtin_amdgcn_mfma_f32_16x16x32_f16(bf[3][0], b0, bo,  0, 0, 0);
      ai = __builtin_amdgcn_mfma_f32_16x16x32_f16(bf[0][1], b1, ai, 0, 0, 0);
      af = __builtin_amdgcn_mfma_f32_16x16x32_f16(bf[1][1], b1, af, 0, 0, 0);
      ag = __builtin_amdgcn_mfma_f32_16x16x32_f16(bf[2][1], b1, ag, 0, 0, 0);
      ao = __builtin_amdgcn_mfma_f32_16x16x32_f16(bf[3][1], b1, ao, 0, 0, 0);
      ai = __builtin_amdgcn_mfma_f32_16x16x16f16(bfx[0], bx[tt], ai, 0, 0, 0);
      af = __builtin_amdgcn_mfma_f32_16x16x16f16(bfx[1], bx[tt], af, 0, 0, 0);
      ag = __builtin_amdgcn_mfma_f32_16x16x16f16(bfx[2], bx[tt], ag, 0, 0, 0);
      ao = __builtin_amdgcn_mfma_f32_16x16x16f16(bfx[3], bx[tt], ao, 0, 0, 0);
      __builtin_amdgcn_s_setprio(0);

      // off-critical-path staging, hidden under MFMA/act latency:
      if (tt == 0) {
        // publish chunk ch+1 into the opposite parity; the regular step
        // barrier publishes it (that parity's last reads were the chunk
        // ch-1 preload burst, >=16 barriers ago).
        union { half8 v; fp16x2 h2[4]; } P;
        P.h2[0] = __builtin_amdgcn_cvt_pkrtz(pa.x, pa.y);
        P.h2[1] = __builtin_amdgcn_cvt_pkrtz(pa.z, pa.w);
        P.h2[2] = __builtin_amdgcn_cvt_pkrtz(pb2.x, pb2.y);
        P.h2[3] = __builtin_amdgcn_cvt_pkrtz(pb2.z, pb2.w);
        *(half8*)&xlds[(ch + 1) & 1][tt_s][row_s][0] = P.v;
      }
      if (tt == 1) {
        // reissue global prefetch (chunk ch+2, wrapped); consumed 15 steps on
        const int chn = (ch + 2 < NCHUNK) ? (ch + 2) : (ch + 2 - NCHUNK);
        pa  = *(const float4*)(xps + (size_t)chn * CHUNK * INn);
        pb2 = *(const float4*)(xps + (size_t)chn * CHUNK * INn + 4);
      }

      // activations: lane's 4 elements = units u0+0..3, batch n
      const floatx2 h01 = act_pair(ai[0], ai[1], af[0], af[1],
                                   ag[0], ag[1], ao[0], ao[1], chat01);
      const floatx2 h23 = act_pair(ai[2], ai[3], af[2], af[3],
                                   ag[2], ag[3], ao[2], ao[3], chat23);

      // packed writeback: 4 consecutive units of batch n -> one b64
      union { half4 v; fp16x2 h2[2]; } Wq;
      Wq.h2[0] = __builtin_amdgcn_cvt_pkrtz(h01.x, h01.y);
      Wq.h2[1] = __builtin_amdgcn_cvt_pkrtz(h23.x, h23.y);
      *(half4*)&hbuf[pn][n][u0] = Wq.v;

      __syncthreads();
    }
  }

  // ---- epilogue: out[b] = h_T[b,:] . W_fc + b_fc   (h_T is in hbuf[0])
  if (tid < 64) {
    const int b = lane & 15;
    const int part = lane >> 4;
    float s = 0.f;
    #pragma unroll
    for (int k = 0; k < 16; ++k) {
      const int uu = part * 16 + k;
      s = __builtin_fmaf((float)hbuf[0][b][uu], W_fc[uu], s);
    }
    s += __shfl_down(s, 32);
    s += __shfl_down(s, 16);
    if (lane < 16) out[bbase + b] = s + b_fc[0];
  }
}

extern "C" void kernel_launch(void* const* d_in, const int* in_sizes, int n_in,
                              void* d_out, int out_size, void* d_ws, size_t ws_size,
                              hipStream_t stream) {
  const float* x    = (const float*)d_in[0];
  const float* W_ih = (const float*)d_in[1];
  const float* W_hh = (const float*)d_in[2];
  const float* b_ih = (const float*)d_in[3];
  const float* b_hh = (const float*)d_in[4];
  const float* W_fc = (const float*)d_in[5];
  const float* b_fc = (const float*)d_in[6];
  float* out = (float*)d_out;
  dim3 grid(Bn / BT), block(256);
  hipLaunchKernelGGL(lstm_fused, grid, block, 0, stream,
                     x, W_ih, W_hh, b_ih, b_hh, W_fc, b_fc, out);
}